// Round 1
// baseline (4997.537 us; speedup 1.0000x reference)
//
#include <hip/hip_runtime.h>
#include <cstdint>

typedef _Float16 f16x8 __attribute__((ext_vector_type(8)));
typedef float    f32x4 __attribute__((ext_vector_type(4)));

#define BB 64
#define TT 256
#define EE 512
#define UU 1024
#define NN 3072   // 3*U

// ---------------- prep: Wh -> f16 MFMA B-fragment layout ----------------
// WhF[((j*3+g)*32 + kb)*64 + lane][jj] = f16(Wh[kb*32 + quad*8 + jj][g*1024 + j*16 + l16])
// where lane = quad*16 + l16.  (B-operand of mfma_f32_16x16x32: n = lane&15, k = (lane>>4)*8 + jj)
__global__ __launch_bounds__(256) void prep_whf(const float* __restrict__ Wh,
                                                _Float16* __restrict__ WhF) {
    int tid  = blockIdx.x * 256 + threadIdx.x;   // 0..393215
    int col8 = tid % 384;                        // group of 8 consecutive columns
    int k    = tid / 384;                        // 0..1023
    int kb = k >> 5, quad = (k >> 3) & 3, jj = k & 7;
    const float* src = Wh + (long)k * NN + col8 * 8;
#pragma unroll
    for (int i = 0; i < 8; i++) {
        int n   = col8 * 8 + i;
        int g   = n >> 10;
        int nl  = n & 1023;
        int j   = nl >> 4, l16 = nl & 15;
        int lane = quad * 16 + l16;
        WhF[((((j * 3 + g) * 32 + kb) * 64 + lane) << 3) + jj] = (_Float16)src[i];
    }
}

__global__ __launch_bounds__(256) void prep_h0(const float* __restrict__ h0,
                                               _Float16* __restrict__ hbuf) {
    int i = blockIdx.x * 256 + threadIdx.x;      // 0..65535
    hbuf[i] = (_Float16)h0[i];
}

// ---------------- embed + input projection GEMM (f16 MFMA) ----------------
// C[i][n] = sum_k emb[tokens[i]][k] * Wx[k][n] + bx[n],  i = b*T + t
// stored as xproj[t][b][n] (f16) for step-contiguous reads in the recurrence.
__global__ __launch_bounds__(256) void proj_kernel(
    const int* __restrict__ tokens, const float* __restrict__ emb,
    const float* __restrict__ Wx, const float* __restrict__ bx,
    _Float16* __restrict__ xproj) {
    int tid  = threadIdx.x;
    int wave = tid >> 6, lane = tid & 63, quad = lane >> 4, l16 = lane & 15;
    int bm = blockIdx.x * 64;           // M offset (i = b*T+t)
    int bn = blockIdx.y * 128;          // N offset
    int wm = (wave & 1) * 32, wn = (wave >> 1) * 64;

    int row0 = bm + wm + l16;
    const float* a0p = emb + (long)tokens[row0] * EE;
    const float* a1p = emb + (long)tokens[row0 + 16] * EE;

    f32x4 acc[2][4];
#pragma unroll
    for (int mt = 0; mt < 2; mt++)
#pragma unroll
        for (int nt = 0; nt < 4; nt++) { f32x4 z = {0.f, 0.f, 0.f, 0.f}; acc[mt][nt] = z; }

#pragma unroll 2
    for (int k0 = 0; k0 < EE; k0 += 32) {
        int ka = k0 + quad * 8;
        f16x8 afr[2];
        {
            const float4* p = (const float4*)(a0p + ka);
            float4 x0 = p[0], x1 = p[1];
            afr[0][0] = (_Float16)x0.x; afr[0][1] = (_Float16)x0.y;
            afr[0][2] = (_Float16)x0.z; afr[0][3] = (_Float16)x0.w;
            afr[0][4] = (_Float16)x1.x; afr[0][5] = (_Float16)x1.y;
            afr[0][6] = (_Float16)x1.z; afr[0][7] = (_Float16)x1.w;
        }
        {
            const float4* p = (const float4*)(a1p + ka);
            float4 x0 = p[0], x1 = p[1];
            afr[1][0] = (_Float16)x0.x; afr[1][1] = (_Float16)x0.y;
            afr[1][2] = (_Float16)x0.z; afr[1][3] = (_Float16)x0.w;
            afr[1][4] = (_Float16)x1.x; afr[1][5] = (_Float16)x1.y;
            afr[1][6] = (_Float16)x1.z; afr[1][7] = (_Float16)x1.w;
        }
        f16x8 bfr[4];
#pragma unroll
        for (int nt = 0; nt < 4; nt++) {
            const float* bp = Wx + (long)ka * NN + (bn + wn + nt * 16 + l16);
#pragma unroll
            for (int jj = 0; jj < 8; jj++) bfr[nt][jj] = (_Float16)bp[(long)jj * NN];
        }
#pragma unroll
        for (int mt = 0; mt < 2; mt++)
#pragma unroll
            for (int nt = 0; nt < 4; nt++)
                acc[mt][nt] = __builtin_amdgcn_mfma_f32_16x16x32_f16(afr[mt], bfr[nt], acc[mt][nt], 0, 0, 0);
    }
    // epilogue: D row = quad*4+r (M index), col = l16 (N index)
#pragma unroll
    for (int mt = 0; mt < 2; mt++) {
        int rowbase = bm + wm + mt * 16 + quad * 4;
#pragma unroll
        for (int nt = 0; nt < 4; nt++) {
            int col = bn + wn + nt * 16 + l16;
            float bias = bx[col];
#pragma unroll
            for (int r = 0; r < 4; r++) {
                int i = rowbase + r;
                int b = i >> 8, t = i & 255;          // T = 256
                xproj[((long)t * BB + b) * NN + col] = (_Float16)(acc[mt][nt][r] + bias);
            }
        }
    }
}

// ---------------- persistent GRU recurrence ----------------
// 64 WGs, WG j owns u-slice [16j,16j+16).  Per step: rec = h @ Wh (M=64,N=48,K=1024 f16 MFMA),
// gates, write h slice + output, device barrier.
__global__ __launch_bounds__(256) void gru_kernel(
    const _Float16* __restrict__ xproj,   // [T][B][3U]
    const _Float16* __restrict__ WhF,     // fragment layout
    const float* __restrict__ hidden,     // [B][U] fp32 h0
    const float* __restrict__ bh,         // [3U]
    _Float16* __restrict__ hbuf,          // [2][B][U]
    unsigned int* cnt,
    float* __restrict__ out) {            // [B][T][U] ++ [B][U]
    int tid  = threadIdx.x;
    int wave = tid >> 6, lane = tid & 63, quad = lane >> 4, l16 = lane & 15;
    int j  = blockIdx.x;
    int u  = j * 16 + l16;
    int b0 = wave * 16;

    float bhz = bh[u], bhr = bh[UU + u], bhh = bh[2 * UU + u];

    float hold[4];
#pragma unroll
    for (int r = 0; r < 4; r++) hold[r] = hidden[(long)(b0 + quad * 4 + r) * UU + u];

    const f16x8* WF = (const f16x8*)WhF;
    const f16x8* Wz = WF + (long)(j * 3 + 0) * 32 * 64 + lane;
    const f16x8* Wr = WF + (long)(j * 3 + 1) * 32 * 64 + lane;
    const f16x8* Wc = WF + (long)(j * 3 + 2) * 32 * 64 + lane;

    for (int t = 0; t < TT; t++) {
        // prefetch x_proj terms for this step (independent of h; issued before MFMA loop)
        const _Float16* xp = xproj + (long)t * BB * NN;
        _Float16 xzv[4], xrv[4], xhv[4];
#pragma unroll
        for (int r = 0; r < 4; r++) {
            const _Float16* p = xp + (long)(b0 + quad * 4 + r) * NN + u;
            xzv[r] = p[0]; xrv[r] = p[UU]; xhv[r] = p[2 * UU];
        }

        const _Float16* h = hbuf + (long)(t & 1) * BB * UU + (long)(b0 + l16) * UU + quad * 8;
        f32x4 az = {0.f, 0.f, 0.f, 0.f}, ar = az, ah = az;
#pragma unroll 4
        for (int kb = 0; kb < 32; kb++) {
            f16x8 afr = *(const f16x8*)(h + kb * 32);
            az = __builtin_amdgcn_mfma_f32_16x16x32_f16(afr, Wz[kb * 64], az, 0, 0, 0);
            ar = __builtin_amdgcn_mfma_f32_16x16x32_f16(afr, Wr[kb * 64], ar, 0, 0, 0);
            ah = __builtin_amdgcn_mfma_f32_16x16x32_f16(afr, Wc[kb * 64], ah, 0, 0, 0);
        }

        _Float16* hw = hbuf + (long)((t + 1) & 1) * BB * UU;
#pragma unroll
        for (int r = 0; r < 4; r++) {
            int b = b0 + quad * 4 + r;
            float z  = 1.f / (1.f + expf(-((float)xzv[r] + az[r] + bhz)));
            float rr = 1.f / (1.f + expf(-((float)xrv[r] + ar[r] + bhr)));
            float cd = tanhf((float)xhv[r] + rr * (ah[r] + bhh));
            float hn = z * hold[r] + (1.f - z) * cd;
            hold[r] = hn;
            out[(long)b * TT * UU + (long)t * UU + u] = hn;
            hw[(long)b * UU + u] = (_Float16)hn;
        }

        if (t != TT - 1) {
            __syncthreads();   // drains vmcnt -> all this WG's h stores are in L2
            if (tid == 0) {
                __hip_atomic_fetch_add(cnt, 1u, __ATOMIC_RELEASE, __HIP_MEMORY_SCOPE_AGENT);
                unsigned tgt = 64u * (unsigned)(t + 1);
                while (__hip_atomic_load(cnt, __ATOMIC_ACQUIRE, __HIP_MEMORY_SCOPE_AGENT) < tgt)
                    __builtin_amdgcn_s_sleep(2);
            }
            __syncthreads();
        }
    }
#pragma unroll
    for (int r = 0; r < 4; r++) {
        int b = b0 + quad * 4 + r;
        out[(long)BB * TT * UU + (long)b * UU + u] = hold[r];
    }
}

// ---------------- launch ----------------
extern "C" void kernel_launch(void* const* d_in, const int* in_sizes, int n_in,
                              void* d_out, int out_size, void* d_ws, size_t ws_size,
                              hipStream_t stream) {
    const int*   tokens = (const int*)d_in[0];
    const float* hidden = (const float*)d_in[1];
    const float* emb    = (const float*)d_in[2];
    const float* Wx     = (const float*)d_in[3];
    const float* bx     = (const float*)d_in[4];
    const float* Wh     = (const float*)d_in[5];
    const float* bh     = (const float*)d_in[6];
    float* out = (float*)d_out;

    // workspace layout (all offsets 256B-aligned)
    char* ws = (char*)d_ws;
    _Float16* xproj = (_Float16*)(ws);                  // 256*64*3072*2   = 100663296 B
    _Float16* WhF   = (_Float16*)(ws + 100663296L);     // 1024*3072*2    =   6291456 B
    _Float16* hbuf  = (_Float16*)(ws + 106954752L);     // 2*64*1024*2    =    262144 B
    unsigned* cnt   = (unsigned*)(ws + 107216896L);     // barrier counter
    if (ws_size < 107217152UL) return;                  // avoid page-faulting on tiny ws

    hipMemsetAsync(cnt, 0, 64, stream);                 // ws is re-poisoned each call
    prep_whf<<<1536, 256, 0, stream>>>(Wh, WhF);
    prep_h0<<<256, 256, 0, stream>>>(hidden, hbuf);
    proj_kernel<<<dim3(256, 24), 256, 0, stream>>>(tokens, emb, Wx, bx, xproj);
    gru_kernel<<<64, 256, 0, stream>>>(xproj, WhF, hidden, bh, hbuf, cnt, out);
}

// Round 2
// 3717.838 us; speedup vs baseline: 1.3442x; 1.3442x over previous
//
#include <hip/hip_runtime.h>
#include <cstdint>

typedef _Float16 f16x8 __attribute__((ext_vector_type(8)));
typedef float    f32x4 __attribute__((ext_vector_type(4)));

#define BB 64
#define TT 256
#define EE 512
#define UU 1024
#define NN 3072   // 3*U

// ---------------- prep: Wh -> f16 MFMA B-fragment layout ----------------
// WhF[((j*3+g)*32 + kb)*64 + lane][jj] = f16(Wh[kb*32 + quad*8 + jj][g*1024 + j*16 + l16])
// where lane = quad*16 + l16.  (B-operand of mfma_f32_16x16x32: n = lane&15, k = (lane>>4)*8 + jj)
__global__ __launch_bounds__(256) void prep_whf(const float* __restrict__ Wh,
                                                _Float16* __restrict__ WhF) {
    int tid  = blockIdx.x * 256 + threadIdx.x;   // 0..393215
    int col8 = tid % 384;                        // group of 8 consecutive columns
    int k    = tid / 384;                        // 0..1023
    int kb = k >> 5, quad = (k >> 3) & 3, jj = k & 7;
    const float* src = Wh + (long)k * NN + col8 * 8;
#pragma unroll
    for (int i = 0; i < 8; i++) {
        int n   = col8 * 8 + i;
        int g   = n >> 10;
        int nl  = n & 1023;
        int j   = nl >> 4, l16 = nl & 15;
        int lane = quad * 16 + l16;
        WhF[((((j * 3 + g) * 32 + kb) * 64 + lane) << 3) + jj] = (_Float16)src[i];
    }
}

__global__ __launch_bounds__(256) void prep_h0(const float* __restrict__ h0,
                                               _Float16* __restrict__ hbuf) {
    int i = blockIdx.x * 256 + threadIdx.x;      // 0..65535
    hbuf[i] = (_Float16)h0[i];
}

// ---------------- embed + input projection GEMM (f16 MFMA) ----------------
__global__ __launch_bounds__(256) void proj_kernel(
    const int* __restrict__ tokens, const float* __restrict__ emb,
    const float* __restrict__ Wx, const float* __restrict__ bx,
    _Float16* __restrict__ xproj) {
    int tid  = threadIdx.x;
    int wave = tid >> 6, lane = tid & 63, quad = lane >> 4, l16 = lane & 15;
    int bm = blockIdx.x * 64;           // M offset (i = b*T+t)
    int bn = blockIdx.y * 128;          // N offset
    int wm = (wave & 1) * 32, wn = (wave >> 1) * 64;

    int row0 = bm + wm + l16;
    const float* a0p = emb + (long)tokens[row0] * EE;
    const float* a1p = emb + (long)tokens[row0 + 16] * EE;

    f32x4 acc[2][4];
#pragma unroll
    for (int mt = 0; mt < 2; mt++)
#pragma unroll
        for (int nt = 0; nt < 4; nt++) { f32x4 z = {0.f, 0.f, 0.f, 0.f}; acc[mt][nt] = z; }

#pragma unroll 2
    for (int k0 = 0; k0 < EE; k0 += 32) {
        int ka = k0 + quad * 8;
        f16x8 afr[2];
        {
            const float4* p = (const float4*)(a0p + ka);
            float4 x0 = p[0], x1 = p[1];
            afr[0][0] = (_Float16)x0.x; afr[0][1] = (_Float16)x0.y;
            afr[0][2] = (_Float16)x0.z; afr[0][3] = (_Float16)x0.w;
            afr[0][4] = (_Float16)x1.x; afr[0][5] = (_Float16)x1.y;
            afr[0][6] = (_Float16)x1.z; afr[0][7] = (_Float16)x1.w;
        }
        {
            const float4* p = (const float4*)(a1p + ka);
            float4 x0 = p[0], x1 = p[1];
            afr[1][0] = (_Float16)x0.x; afr[1][1] = (_Float16)x0.y;
            afr[1][2] = (_Float16)x0.z; afr[1][3] = (_Float16)x0.w;
            afr[1][4] = (_Float16)x1.x; afr[1][5] = (_Float16)x1.y;
            afr[1][6] = (_Float16)x1.z; afr[1][7] = (_Float16)x1.w;
        }
        f16x8 bfr[4];
#pragma unroll
        for (int nt = 0; nt < 4; nt++) {
            const float* bp = Wx + (long)ka * NN + (bn + wn + nt * 16 + l16);
#pragma unroll
            for (int jj = 0; jj < 8; jj++) bfr[nt][jj] = (_Float16)bp[(long)jj * NN];
        }
#pragma unroll
        for (int mt = 0; mt < 2; mt++)
#pragma unroll
            for (int nt = 0; nt < 4; nt++)
                acc[mt][nt] = __builtin_amdgcn_mfma_f32_16x16x32_f16(afr[mt], bfr[nt], acc[mt][nt], 0, 0, 0);
    }
#pragma unroll
    for (int mt = 0; mt < 2; mt++) {
        int rowbase = bm + wm + mt * 16 + quad * 4;
#pragma unroll
        for (int nt = 0; nt < 4; nt++) {
            int col = bn + wn + nt * 16 + l16;
            float bias = bx[col];
#pragma unroll
            for (int r = 0; r < 4; r++) {
                int i = rowbase + r;
                int b = i >> 8, t = i & 255;          // T = 256
                xproj[((long)t * BB + b) * NN + col] = (_Float16)(acc[mt][nt][r] + bias);
            }
        }
    }
}

// ---------------- persistent GRU recurrence ----------------
// 64 WGs (1 per CU used), WG j owns u-slice [16j,16j+16).
// KEY CHANGE vs R0: the per-WG Wh slice (96 KB = 384 VGPR/lane) is loaded into
// registers ONCE before the t-loop. Registers are immune to the per-step
// acquire-invalidate that was forcing a 96 KB L3/HBM refetch every step
// (R0: FETCH_SIZE 331 MB, 440 cyc/load serialized -> 17.8 us/step).
// 1 WG/CU -> 1 wave/SIMD -> 512-VGPR budget available.
__global__ __launch_bounds__(256, 1) void gru_kernel(
    const _Float16* __restrict__ xproj,   // [T][B][3U]
    const _Float16* __restrict__ WhF,     // fragment layout
    const float* __restrict__ hidden,     // [B][U] fp32 h0
    const float* __restrict__ bh,         // [3U]
    _Float16* __restrict__ hbuf,          // [2][B][U]
    unsigned int* cnt,
    float* __restrict__ out) {            // [B][T][U] ++ [B][U]
    int tid  = threadIdx.x;
    int wave = tid >> 6, lane = tid & 63, quad = lane >> 4, l16 = lane & 15;
    int j  = blockIdx.x;
    int u  = j * 16 + l16;
    int b0 = wave * 16;

    float bhz = bh[u], bhr = bh[UU + u], bhh = bh[2 * UU + u];

    float hold[4];
#pragma unroll
    for (int r = 0; r < 4; r++) hold[r] = hidden[(long)(b0 + quad * 4 + r) * UU + u];

    // ---- load the whole per-WG weight slice into registers (384 VGPRs) ----
    const f16x8* WF = (const f16x8*)WhF + (long)j * 3 * 32 * 64 + lane;
    f16x8 w[96];                      // w[g*32+kb]
#pragma unroll
    for (int i = 0; i < 96; i++) w[i] = WF[(long)i * 64];

#pragma unroll 1
    for (int t = 0; t < TT; t++) {
        // x_proj terms for this step (independent of h; issued before MFMA loop)
        const _Float16* xp = xproj + (long)t * BB * NN;
        float xzv[4], xrv[4], xhv[4];
#pragma unroll
        for (int r = 0; r < 4; r++) {
            const _Float16* p = xp + (long)(b0 + quad * 4 + r) * NN + u;
            xzv[r] = (float)p[0]; xrv[r] = (float)p[UU]; xhv[r] = (float)p[2 * UU];
        }

        const _Float16* h = hbuf + (long)(t & 1) * BB * UU + (long)(b0 + l16) * UU + quad * 8;
        f32x4 az = {0.f, 0.f, 0.f, 0.f}, ar = az, ah = az;
#pragma unroll
        for (int kb = 0; kb < 32; kb++) {
            f16x8 afr = *(const f16x8*)(h + kb * 32);
            az = __builtin_amdgcn_mfma_f32_16x16x32_f16(afr, w[kb],      az, 0, 0, 0);
            ar = __builtin_amdgcn_mfma_f32_16x16x32_f16(afr, w[32 + kb], ar, 0, 0, 0);
            ah = __builtin_amdgcn_mfma_f32_16x16x32_f16(afr, w[64 + kb], ah, 0, 0, 0);
        }

        _Float16* hw = hbuf + (long)((t + 1) & 1) * BB * UU;
#pragma unroll
        for (int r = 0; r < 4; r++) {
            int b = b0 + quad * 4 + r;
            float z  = 1.f / (1.f + expf(-(xzv[r] + az[r] + bhz)));
            float rr = 1.f / (1.f + expf(-(xrv[r] + ar[r] + bhr)));
            float cd = tanhf(xhv[r] + rr * (ah[r] + bhh));
            float hn = z * hold[r] + (1.f - z) * cd;
            hold[r] = hn;
            out[(long)b * TT * UU + (long)t * UU + u] = hn;
            hw[(long)b * UU + u] = (_Float16)hn;
        }

        if (t != TT - 1) {
            __syncthreads();   // drains vmcnt -> this WG's h stores are in L2
            if (tid == 0) {
                // release: wbl2 so our h lines reach IC/L3 before signaling
                __hip_atomic_fetch_add(cnt, 1u, __ATOMIC_RELEASE, __HIP_MEMORY_SCOPE_AGENT);
                unsigned tgt = 64u * (unsigned)(t + 1);
                // relaxed spin (no per-poll cache invalidate), single acquire after
                while (__hip_atomic_load(cnt, __ATOMIC_RELAXED, __HIP_MEMORY_SCOPE_AGENT) < tgt)
                    __builtin_amdgcn_s_sleep(2);
                __builtin_amdgcn_fence(__ATOMIC_ACQUIRE, "agent");
            }
            __syncthreads();
        }
    }
#pragma unroll
    for (int r = 0; r < 4; r++) {
        int b = b0 + quad * 4 + r;
        out[(long)BB * TT * UU + (long)b * UU + u] = hold[r];
    }
}

// ---------------- launch ----------------
extern "C" void kernel_launch(void* const* d_in, const int* in_sizes, int n_in,
                              void* d_out, int out_size, void* d_ws, size_t ws_size,
                              hipStream_t stream) {
    const int*   tokens = (const int*)d_in[0];
    const float* hidden = (const float*)d_in[1];
    const float* emb    = (const float*)d_in[2];
    const float* Wx     = (const float*)d_in[3];
    const float* bx     = (const float*)d_in[4];
    const float* Wh     = (const float*)d_in[5];
    const float* bh     = (const float*)d_in[6];
    float* out = (float*)d_out;

    char* ws = (char*)d_ws;
    _Float16* xproj = (_Float16*)(ws);                  // 100663296 B
    _Float16* WhF   = (_Float16*)(ws + 100663296L);     //   6291456 B
    _Float16* hbuf  = (_Float16*)(ws + 106954752L);     //    262144 B
    unsigned* cnt   = (unsigned*)(ws + 107216896L);
    if (ws_size < 107217152UL) return;

    hipMemsetAsync(cnt, 0, 64, stream);
    prep_whf<<<1536, 256, 0, stream>>>(Wh, WhF);
    prep_h0<<<256, 256, 0, stream>>>(hidden, hbuf);
    proj_kernel<<<dim3(256, 24), 256, 0, stream>>>(tokens, emb, Wx, bx, xproj);
    gru_kernel<<<64, 256, 0, stream>>>(xproj, WhF, hidden, bh, hbuf, cnt, out);
}

// Round 3
// 2898.407 us; speedup vs baseline: 1.7242x; 1.2827x over previous
//
#include <hip/hip_runtime.h>
#include <cstdint>

typedef _Float16 f16x8 __attribute__((ext_vector_type(8)));
typedef float    f32x4 __attribute__((ext_vector_type(4)));

#define BB 64
#define TT 256
#define EE 512
#define UU 1024
#define NN 3072   // 3*U

// ---------------- prep: Wh -> f16 MFMA B-fragment layout ----------------
// WhF[((j*3+g)*32 + kb)*64 + lane][jj] = f16(Wh[kb*32 + quad*8 + jj][g*1024 + j*16 + l16])
// lane = quad*16 + l16.  (B-operand of mfma_f32_16x16x32: n = lane&15, k = (lane>>4)*8 + jj)
__global__ __launch_bounds__(256) void prep_whf(const float* __restrict__ Wh,
                                                _Float16* __restrict__ WhF) {
    int tid  = blockIdx.x * 256 + threadIdx.x;   // 0..393215
    int col8 = tid % 384;                        // group of 8 consecutive columns
    int k    = tid / 384;                        // 0..1023
    int kb = k >> 5, quad = (k >> 3) & 3, jj = k & 7;
    const float* src = Wh + (long)k * NN + col8 * 8;
#pragma unroll
    for (int i = 0; i < 8; i++) {
        int n   = col8 * 8 + i;
        int g   = n >> 10;
        int nl  = n & 1023;
        int j   = nl >> 4, l16 = nl & 15;
        int lane = quad * 16 + l16;
        WhF[((((j * 3 + g) * 32 + kb) * 64 + lane) << 3) + jj] = (_Float16)src[i];
    }
}

__global__ __launch_bounds__(256) void prep_h0(const float* __restrict__ h0,
                                               _Float16* __restrict__ hbuf) {
    int i = blockIdx.x * 256 + threadIdx.x;      // 0..65535
    hbuf[i] = (_Float16)h0[i];
}

// ---------------- embed + input projection GEMM (f16 MFMA) ----------------
__global__ __launch_bounds__(256) void proj_kernel(
    const int* __restrict__ tokens, const float* __restrict__ emb,
    const float* __restrict__ Wx, const float* __restrict__ bx,
    _Float16* __restrict__ xproj) {
    int tid  = threadIdx.x;
    int wave = tid >> 6, lane = tid & 63, quad = lane >> 4, l16 = lane & 15;
    int bm = blockIdx.x * 64;           // M offset (i = b*T+t)
    int bn = blockIdx.y * 128;          // N offset
    int wm = (wave & 1) * 32, wn = (wave >> 1) * 64;

    int row0 = bm + wm + l16;
    const float* a0p = emb + (long)tokens[row0] * EE;
    const float* a1p = emb + (long)tokens[row0 + 16] * EE;

    f32x4 acc[2][4];
#pragma unroll
    for (int mt = 0; mt < 2; mt++)
#pragma unroll
        for (int nt = 0; nt < 4; nt++) { f32x4 z = {0.f, 0.f, 0.f, 0.f}; acc[mt][nt] = z; }

#pragma unroll 2
    for (int k0 = 0; k0 < EE; k0 += 32) {
        int ka = k0 + quad * 8;
        f16x8 afr[2];
        {
            const float4* p = (const float4*)(a0p + ka);
            float4 x0 = p[0], x1 = p[1];
            afr[0][0] = (_Float16)x0.x; afr[0][1] = (_Float16)x0.y;
            afr[0][2] = (_Float16)x0.z; afr[0][3] = (_Float16)x0.w;
            afr[0][4] = (_Float16)x1.x; afr[0][5] = (_Float16)x1.y;
            afr[0][6] = (_Float16)x1.z; afr[0][7] = (_Float16)x1.w;
        }
        {
            const float4* p = (const float4*)(a1p + ka);
            float4 x0 = p[0], x1 = p[1];
            afr[1][0] = (_Float16)x0.x; afr[1][1] = (_Float16)x0.y;
            afr[1][2] = (_Float16)x0.z; afr[1][3] = (_Float16)x0.w;
            afr[1][4] = (_Float16)x1.x; afr[1][5] = (_Float16)x1.y;
            afr[1][6] = (_Float16)x1.z; afr[1][7] = (_Float16)x1.w;
        }
        f16x8 bfr[4];
#pragma unroll
        for (int nt = 0; nt < 4; nt++) {
            const float* bp = Wx + (long)ka * NN + (bn + wn + nt * 16 + l16);
#pragma unroll
            for (int jj = 0; jj < 8; jj++) bfr[nt][jj] = (_Float16)bp[(long)jj * NN];
        }
#pragma unroll
        for (int mt = 0; mt < 2; mt++)
#pragma unroll
            for (int nt = 0; nt < 4; nt++)
                acc[mt][nt] = __builtin_amdgcn_mfma_f32_16x16x32_f16(afr[mt], bfr[nt], acc[mt][nt], 0, 0, 0);
    }
#pragma unroll
    for (int mt = 0; mt < 2; mt++) {
        int rowbase = bm + wm + mt * 16 + quad * 4;
#pragma unroll
        for (int nt = 0; nt < 4; nt++) {
            int col = bn + wn + nt * 16 + l16;
            float bias = bx[col];
#pragma unroll
            for (int r = 0; r < 4; r++) {
                int i = rowbase + r;
                int b = i >> 8, t = i & 255;          // T = 256
                xproj[((long)t * BB + b) * NN + col] = (_Float16)(acc[mt][nt][r] + bias);
            }
        }
    }
}

// ---------------- persistent GRU recurrence ----------------
// 64 WGs (1/CU), WG j owns u-slice [16j,16j+16).
// R2 KEY CHANGE: force the 96 weight fragments to stay register-resident.
// R1's plain array failed: 384 regs > 256 arch-VGPR encoding limit, so the
// compiler sank the loads back into the t-loop (FETCH_SIZE stayed 331 MB).
// Fix: no-op inline-asm pins — "+a" forces AGPR residency (60 frags = 240
// AGPRs), "+v" forces VGPR residency (36 frags = 144 VGPRs). The asm is an
// opaque producer: cannot be rematerialized or sunk. MFMA intrinsic operands
// are AV-class on gfx950 (read AGPR directly), and hazards stay
// compiler-managed since we keep the intrinsic.
__global__ __launch_bounds__(256, 1) void gru_kernel(
    const _Float16* __restrict__ xproj,   // [T][B][3U]
    const _Float16* __restrict__ WhF,     // fragment layout
    const float* __restrict__ hidden,     // [B][U] fp32 h0
    const float* __restrict__ bh,         // [3U]
    _Float16* __restrict__ hbuf,          // [2][B][U]
    unsigned int* cnt,
    float* __restrict__ out) {            // [B][T][U] ++ [B][U]
    int tid  = threadIdx.x;
    int wave = tid >> 6, lane = tid & 63, quad = lane >> 4, l16 = lane & 15;
    int j  = blockIdx.x;
    int u  = j * 16 + l16;
    int b0 = wave * 16;

    float bhz = bh[u], bhr = bh[UU + u], bhh = bh[2 * UU + u];

    float hold[4];
#pragma unroll
    for (int r = 0; r < 4; r++) hold[r] = hidden[(long)(b0 + quad * 4 + r) * UU + u];

    // ---- load the whole per-WG weight slice into registers, ONCE ----
    const f16x8* WF = (const f16x8*)WhF + (long)j * 3 * 32 * 64 + lane;
    f16x8 w[96];                      // w[g*32+kb]
#pragma unroll
    for (int i = 0; i < 96; i++) w[i] = WF[(long)i * 64];
    // pin: 60 fragments -> AGPRs (240), 36 -> VGPRs (144)
#pragma unroll
    for (int i = 0; i < 60; i++) asm volatile("" : "+a"(w[i]));
#pragma unroll
    for (int i = 60; i < 96; i++) asm volatile("" : "+v"(w[i]));

#pragma unroll 1
    for (int t = 0; t < TT; t++) {
        const _Float16* xp = xproj + (long)t * BB * NN;
        float xzv[4], xrv[4], xhv[4];
#pragma unroll
        for (int r = 0; r < 4; r++) {
            const _Float16* p = xp + (long)(b0 + quad * 4 + r) * NN + u;
            xzv[r] = (float)p[0]; xrv[r] = (float)p[UU]; xhv[r] = (float)p[2 * UU];
        }

        const _Float16* h = hbuf + (long)(t & 1) * BB * UU + (long)(b0 + l16) * UU + quad * 8;
        f32x4 az = {0.f, 0.f, 0.f, 0.f}, ar = az, ah = az;
#pragma unroll
        for (int kb = 0; kb < 32; kb++) {
            f16x8 afr = *(const f16x8*)(h + kb * 32);
            az = __builtin_amdgcn_mfma_f32_16x16x32_f16(afr, w[kb],      az, 0, 0, 0);
            ar = __builtin_amdgcn_mfma_f32_16x16x32_f16(afr, w[32 + kb], ar, 0, 0, 0);
            ah = __builtin_amdgcn_mfma_f32_16x16x32_f16(afr, w[64 + kb], ah, 0, 0, 0);
        }

        _Float16* hw = hbuf + (long)((t + 1) & 1) * BB * UU;
#pragma unroll
        for (int r = 0; r < 4; r++) {
            int b = b0 + quad * 4 + r;
            float z  = 1.f / (1.f + expf(-(xzv[r] + az[r] + bhz)));
            float rr = 1.f / (1.f + expf(-(xrv[r] + ar[r] + bhr)));
            float cd = tanhf(xhv[r] + rr * (ah[r] + bhh));
            float hn = z * hold[r] + (1.f - z) * cd;
            hold[r] = hn;
            out[(long)b * TT * UU + (long)t * UU + u] = hn;
            hw[(long)b * UU + u] = (_Float16)hn;
        }

        if (t != TT - 1) {
            __syncthreads();   // drains vmcnt -> this WG's h stores visible
            if (tid == 0) {
                __hip_atomic_fetch_add(cnt, 1u, __ATOMIC_RELEASE, __HIP_MEMORY_SCOPE_AGENT);
                unsigned tgt = 64u * (unsigned)(t + 1);
                while (__hip_atomic_load(cnt, __ATOMIC_RELAXED, __HIP_MEMORY_SCOPE_AGENT) < tgt)
                    __builtin_amdgcn_s_sleep(1);
                __builtin_amdgcn_fence(__ATOMIC_ACQUIRE, "agent");
            }
            __syncthreads();
        }
    }
#pragma unroll
    for (int r = 0; r < 4; r++) {
        int b = b0 + quad * 4 + r;
        out[(long)BB * TT * UU + (long)b * UU + u] = hold[r];
    }
}

// ---------------- launch ----------------
extern "C" void kernel_launch(void* const* d_in, const int* in_sizes, int n_in,
                              void* d_out, int out_size, void* d_ws, size_t ws_size,
                              hipStream_t stream) {
    const int*   tokens = (const int*)d_in[0];
    const float* hidden = (const float*)d_in[1];
    const float* emb    = (const float*)d_in[2];
    const float* Wx     = (const float*)d_in[3];
    const float* bx     = (const float*)d_in[4];
    const float* Wh     = (const float*)d_in[5];
    const float* bh     = (const float*)d_in[6];
    float* out = (float*)d_out;

    char* ws = (char*)d_ws;
    _Float16* xproj = (_Float16*)(ws);                  // 100663296 B
    _Float16* WhF   = (_Float16*)(ws + 100663296L);     //   6291456 B
    _Float16* hbuf  = (_Float16*)(ws + 106954752L);     //    262144 B
    unsigned* cnt   = (unsigned*)(ws + 107216896L);
    if (ws_size < 107217152UL) return;

    hipMemsetAsync(cnt, 0, 64, stream);
    prep_whf<<<1536, 256, 0, stream>>>(Wh, WhF);
    prep_h0<<<256, 256, 0, stream>>>(hidden, hbuf);
    proj_kernel<<<dim3(256, 24), 256, 0, stream>>>(tokens, emb, Wx, bx, xproj);
    gru_kernel<<<64, 256, 0, stream>>>(xproj, WhF, hidden, bh, hbuf, cnt, out);
}